// Round 2
// baseline (206.150 us; speedup 1.0000x reference)
//
#include <hip/hip_runtime.h>

#define N_NODES 100000
#define N_EDGES 600000
#define H 128
#define CAP 31                                           // senders per line (word0 = count). Poisson(6): P(deg>31) ~ 1e-24
#define LINE 32                                          // ints per receiver line = 128 B

#define NB_FILL ((N_EDGES + 255) / 256)                  // 2344
#define NB_PREP 16
#define NB_CONV4 3125                                    // convert blocks: 1024 float4 each (exact)

#define BLK_NODES 64
#define N_BLKS ((N_NODES + BLK_NODES - 1) / BLK_NODES)   // 1563

typedef short v8s __attribute__((ext_vector_type(8)));   // 8 bf16 (4 VGPRs)
typedef float v4f __attribute__((ext_vector_type(4)));   // 4 fp32 acc

__device__ __forceinline__ unsigned short f2bf(float f) {
    unsigned int u = __float_as_uint(f);
    u = (u + 0x7fffu + ((u >> 16) & 1u)) >> 16;   // round-nearest-even
    return (unsigned short)u;
}
__device__ __forceinline__ unsigned int pack2bf(float a, float b) {
    return (unsigned int)f2bf(a) | ((unsigned int)f2bf(b) << 16);
}
__device__ __forceinline__ void accum8(float* a, uint4 u) {
    a[0] += __uint_as_float(u.x << 16);
    a[1] += __uint_as_float(u.x & 0xffff0000u);
    a[2] += __uint_as_float(u.y << 16);
    a[3] += __uint_as_float(u.y & 0xffff0000u);
    a[4] += __uint_as_float(u.z << 16);
    a[5] += __uint_as_float(u.z & 0xffff0000u);
    a[6] += __uint_as_float(u.w << 16);
    a[7] += __uint_as_float(u.w & 0xffff0000u);
}

// ---------------------------------------------------------------------------
// Prep (one dispatch, role by blockIdx). Role order: FILL first (latency-
// bound, starts at t=0), then weight permute, then x->bf16 convert (BW-bound
// backfill).
// R8: per-receiver OWN 128B line [count, s0..s30]. The old dense cnt[]
// packed 32 counters/line -> ~192 cross-XCD atomic RMWs per line (false
// sharing was the 62us). Now each line sees only ~deg(r)+1 ops, and the
// position store lands in the SAME line as its atomic. Slot store stays
// non-temporal (R7: word-granular dirty masks make mixed atomic+NT on one
// line safe - proven by R7's cross-XCD 4B scatters).
// ---------------------------------------------------------------------------
__global__ __launch_bounds__(256) void prep_fused_kernel(
    const float* __restrict__ x, unsigned int* __restrict__ xb4,
    const float* __restrict__ Ws, const float* __restrict__ Wm,
    unsigned short* __restrict__ Bperm,
    const int* __restrict__ senders, const int* __restrict__ receivers,
    int* __restrict__ lines)
{
    int b = blockIdx.x;
    if (b < NB_FILL) {
        int e = b * 256 + threadIdx.x;
        if (e < N_EDGES) {
            int r = receivers[e];
            int s = senders[e];
            int pos = atomicAdd(&lines[r * LINE], 1);
            if (pos < CAP) __builtin_nontemporal_store(s, &lines[r * LINE + 1 + pos]);
        }
    } else if (b < NB_FILL + NB_PREP) {
        // B-fragment permute: frag f=(kstep*8+ntile)*64+lane holds
        // B[k=kstep*32+q*8+j][n=ntile*16+(lane&15)], B=[Ws;Wm] (K=256,N=128)
        int t = (b - NB_FILL) * 256 + threadIdx.x; // 0..4095
        int kstep = t >> 9;
        int ntile = (t >> 6) & 7;
        int lane  = t & 63;
        int q = lane >> 4;
        int n = ntile * 16 + (lane & 15);
#pragma unroll
        for (int j = 0; j < 8; ++j) {
            int k = kstep * 32 + q * 8 + j;
            float v = (k < H) ? Ws[k * H + n] : Wm[(k - H) * H + n];
            Bperm[(size_t)t * 8 + j] = f2bf(v);
        }
    } else {
        int base = (b - NB_FILL - NB_PREP) * 1024 + threadIdx.x;
#pragma unroll
        for (int k = 0; k < 4; ++k) {
            int i = base + k * 256;                // float4 index
            float4 v = ((const float4*)x)[i];
            uint2 o;
            o.x = pack2bf(v.x, v.y);
            o.y = pack2bf(v.z, v.w);
            ((uint2*)xb4)[i] = o;
        }
    }
}

// ---------------------------------------------------------------------------
// Fused gather + MFMA GEMM. Block owns 64 nodes.
// Phase A: wave w gathers nodes [w*16, w*16+16): reads its line (count +
//   senders in ONE 128B fetch), accumulates neighbor rows in fp32, writes
//   normalized agg rows to LDS (MFMA-A chunk layout, node dim padded to 65).
// Phase B: wave w computes n-tiles {2w,2w+1} for all 64 rows.
//   R8: the x-part A-fragment IS a row-major 16B read of xb (lane mr ->
//   row node_base+s*16+mr, coalesced) - no transpose, no LDS needed. Only
//   agg (a cross-wave shuffle) stays in LDS. LDS 33.3KB -> 16.6KB lifts
//   the LDS occupancy cap 4 -> 8 blocks/CU (VGPR 52 permits 8 naturally;
//   no min-waves pin, to avoid forcing spills).
// ---------------------------------------------------------------------------
__global__ __launch_bounds__(256) void gather_gemm_kernel(
    const unsigned short* __restrict__ xb,
    const int* __restrict__ lines,
    const unsigned short* __restrict__ Bperm,
    const float* __restrict__ bias,
    float* __restrict__ out)
{
    __shared__ unsigned short tile[16][65][8];      // agg only, 16.6 KB

    const int t = threadIdx.x;
    const int w = t >> 6;
    const int lane = t & 63;
    const int node_base = blockIdx.x * BLK_NODES;
    const int sub = (lane >> 4) & 3;   // node within group of 4
    const int li  = lane & 15;         // column chunk (8 bf16 = 16 B)

    // ---- Phase A: gather + stage agg ----
    for (int g = 0; g < 4; ++g) {
        int nl = w * 16 + g * 4 + sub;             // node_local 0..63
        int node = node_base + nl;
        float a[8];
#pragma unroll
        for (int i = 0; i < 8; ++i) a[i] = 0.f;
        int d_true = 0;
        if (node < N_NODES) {
            const int* ln = lines + (size_t)node * LINE;
            d_true = ln[0];
            int d = d_true < CAP ? d_true : CAP;
            const int* sl = ln + 1;
            int e = 0;
            for (; e + 3 < d; e += 4) {
                int i0 = sl[e];
                int i1 = sl[e + 1];
                int i2 = sl[e + 2];
                int i3 = sl[e + 3];
                uint4 u0 = *(const uint4*)(xb + (size_t)i0 * H + li * 8);
                uint4 u1 = *(const uint4*)(xb + (size_t)i1 * H + li * 8);
                uint4 u2 = *(const uint4*)(xb + (size_t)i2 * H + li * 8);
                uint4 u3 = *(const uint4*)(xb + (size_t)i3 * H + li * 8);
                accum8(a, u0);
                accum8(a, u1);
                accum8(a, u2);
                accum8(a, u3);
            }
            for (; e < d; ++e) {
                uint4 u0 = *(const uint4*)(xb + (size_t)sl[e] * H + li * 8);
                accum8(a, u0);
            }
        }
        float inv = 1.0f / fmaxf((float)d_true, 1.0f);
        uint4 o;
        o.x = pack2bf(a[0] * inv, a[1] * inv);
        o.y = pack2bf(a[2] * inv, a[3] * inv);
        o.z = pack2bf(a[4] * inv, a[5] * inv);
        o.w = pack2bf(a[6] * inv, a[7] * inv);
        *(uint4*)&tile[li][nl][0] = o;
    }
    __syncthreads();

    // ---- Phase B: GEMM, wave w owns n-tiles 2w and 2w+1 ----
    const int q  = lane >> 4;
    const int mr = lane & 15;

    // x-part A row pointers (row-clamped; OOB rows never stored)
    const unsigned short* pA[4];
#pragma unroll
    for (int s = 0; s < 4; ++s) {
        int row = node_base + s * 16 + mr;
        if (row > N_NODES - 1) row = N_NODES - 1;
        pA[s] = xb + (size_t)row * H;
    }

    v4f acc[4][2];
#pragma unroll
    for (int j = 0; j < 2; ++j) {
        float bv = bias[(2 * w + j) * 16 + mr];
#pragma unroll
        for (int s = 0; s < 4; ++s) acc[s][j] = (v4f){bv, bv, bv, bv};
    }

    const v8s* bp = (const v8s*)Bperm;
#pragma unroll
    for (int ks = 0; ks < 8; ++ks) {
        int lic = (ks & 3) * 4 + q;        // chunk holding cols [ks*32+q*8, +8)
        v8s a2[4];
        if (ks < 4) {
            // x part (K 0..127): straight from global, coalesced 64B/row
#pragma unroll
            for (int s = 0; s < 4; ++s)
                a2[s] = *(const v8s*)(pA[s] + lic * 8);
        } else {
            // agg part (K 128..255): from LDS
#pragma unroll
            for (int s = 0; s < 4; ++s)
                a2[s] = *(const v8s*)&tile[lic][s * 16 + mr][0];
        }
#pragma unroll
        for (int j = 0; j < 2; ++j) {
            v8s bfrag = bp[(ks * 8 + 2 * w + j) * 64 + lane];
#pragma unroll
            for (int s = 0; s < 4; ++s)
                acc[s][j] = __builtin_amdgcn_mfma_f32_16x16x32_bf16(a2[s], bfrag, acc[s][j], 0, 0, 0);
        }
    }

    // ---- epilogue: bias already in acc; ReLU + store ----
#pragma unroll
    for (int s = 0; s < 4; ++s) {
#pragma unroll
        for (int r = 0; r < 4; ++r) {
            int row = node_base + s * 16 + q * 4 + r;
            if (row < N_NODES) {
#pragma unroll
                for (int j = 0; j < 2; ++j)
                    out[(size_t)row * H + (2 * w + j) * 16 + mr] = fmaxf(acc[s][j][r], 0.f);
            }
        }
    }
}

extern "C" void kernel_launch(void* const* d_in, const int* in_sizes, int n_in,
                              void* d_out, int out_size, void* d_ws, size_t ws_size,
                              hipStream_t stream) {
    const float* x        = (const float*)d_in[0];
    const int*   senders  = (const int*)d_in[1];
    const int*   receivers= (const int*)d_in[2];
    const float* Ws       = (const float*)d_in[3];
    const float* Wm       = (const float*)d_in[4];
    const float* bias     = (const float*)d_in[5];
    float*       out      = (float*)d_out;

    // workspace layout (~38.5 MB)
    char* p = (char*)d_ws;
    unsigned short* xb    = (unsigned short*)p; p += (size_t)N_NODES * H * sizeof(unsigned short); // 25.6 MB
    unsigned short* Bperm = (unsigned short*)p; p += (size_t)256 * H * sizeof(unsigned short);     // 64 KB
    int* lines = (int*)p; p += (size_t)N_NODES * LINE * sizeof(int);                               // 12.8 MB

    hipMemsetAsync(lines, 0, (size_t)N_NODES * LINE * sizeof(int), stream);

    prep_fused_kernel<<<NB_FILL + NB_PREP + NB_CONV4, 256, 0, stream>>>(
        x, (unsigned int*)xb, Ws, Wm, Bperm, senders, receivers, lines);
    gather_gemm_kernel<<<N_BLKS, 256, 0, stream>>>(xb, lines, Bperm, bias, out);
}

// Round 3
// 186.223 us; speedup vs baseline: 1.1070x; 1.1070x over previous
//
#include <hip/hip_runtime.h>

#define N_NODES 100000
#define N_EDGES 600000
#define H 128
#define CAP 32                                           // bucket capacity (Poisson(6), P(>32)~1e-9)

#define NB_FILL 586                                      // 1024 edges/block, 4 per thread
#define NB_PREP 16
#define NB_CONV4 3125                                    // convert blocks: 1024 float4 each (exact)
#define NB_TOTAL (NB_FILL * 6 + (NB_PREP + NB_CONV4 - NB_FILL * 5))  // 3727 = 586 + 16 + 3125

#define BLK_NODES 64
#define N_BLKS ((N_NODES + BLK_NODES - 1) / BLK_NODES)   // 1563

typedef short v8s __attribute__((ext_vector_type(8)));   // 8 bf16 (4 VGPRs)
typedef float v4f __attribute__((ext_vector_type(4)));   // 4 fp32 acc

__device__ __forceinline__ unsigned short f2bf(float f) {
    unsigned int u = __float_as_uint(f);
    u = (u + 0x7fffu + ((u >> 16) & 1u)) >> 16;   // round-nearest-even
    return (unsigned short)u;
}
__device__ __forceinline__ unsigned int pack2bf(float a, float b) {
    return (unsigned int)f2bf(a) | ((unsigned int)f2bf(b) << 16);
}
__device__ __forceinline__ void accum8(float* a, uint4 u) {
    a[0] += __uint_as_float(u.x << 16);
    a[1] += __uint_as_float(u.x & 0xffff0000u);
    a[2] += __uint_as_float(u.y << 16);
    a[3] += __uint_as_float(u.y & 0xffff0000u);
    a[4] += __uint_as_float(u.z << 16);
    a[5] += __uint_as_float(u.z & 0xffff0000u);
    a[6] += __uint_as_float(u.w << 16);
    a[7] += __uint_as_float(u.w & 0xffff0000u);
}

// ---------------------------------------------------------------------------
// Prep (one dispatch, role by blockIdx).
// R9 change: INTERLEAVED roles. R2 proved per-receiver-line privatization is
// a null (prep ~60us either way) -> FILL is bound by the atomic round-trip /
// scattered-write path itself, not line contention. Old layout ran 2344
// latency-bound FILL blocks first (they fill all 2048 resident slots,
// VALUBusy 2%, machine idle), THEN the BW-bound CONV blocks. Now FILL is
// every 6th block so each CU always holds ~1 FILL + ~5 CONV blocks: CONV's
// streaming BW hides FILL's atomic latency. FILL also takes 4 edges/thread
// (4 independent atomic chains in flight per lane instead of 1).
// Dense cnt[] is back (R2 null result) -> memset is 400KB again.
// ---------------------------------------------------------------------------
__global__ __launch_bounds__(256) void prep_fused_kernel(
    const float* __restrict__ x, unsigned int* __restrict__ xb4,
    const float* __restrict__ Ws, const float* __restrict__ Wm,
    unsigned short* __restrict__ Bperm,
    const int* __restrict__ senders, const int* __restrict__ receivers,
    int* __restrict__ cnt, int* __restrict__ slots)
{
    int b = blockIdx.x;
    bool isfill = (b % 6 == 0) && (b / 6 < NB_FILL);
    if (isfill) {
        int e = (b / 6) * 1024 + threadIdx.x;
#pragma unroll
        for (int k = 0; k < 4; ++k, e += 256) {
            if (e < N_EDGES) {
                int r = receivers[e];
                int s = senders[e];
                int pos = atomicAdd(&cnt[r], 1);
                if (pos < CAP) __builtin_nontemporal_store(s, &slots[r * CAP + pos]);
            }
        }
    } else {
        // non-fill ordinal: blocks b<NB_FILL*6 skip one fill block per 6;
        // beyond that range all blocks are non-fill.
        int o = (b < NB_FILL * 6) ? (b - b / 6 - 1) : (b - NB_FILL);
        if (o < NB_PREP) {
            // B-fragment permute: frag f=(kstep*8+ntile)*64+lane holds
            // B[k=kstep*32+q*8+j][n=ntile*16+(lane&15)], B=[Ws;Wm] (K=256,N=128)
            int t = o * 256 + threadIdx.x; // 0..4095
            int kstep = t >> 9;
            int ntile = (t >> 6) & 7;
            int lane  = t & 63;
            int q = lane >> 4;
            int n = ntile * 16 + (lane & 15);
#pragma unroll
            for (int j = 0; j < 8; ++j) {
                int k = kstep * 32 + q * 8 + j;
                float v = (k < H) ? Ws[k * H + n] : Wm[(k - H) * H + n];
                Bperm[(size_t)t * 8 + j] = f2bf(v);
            }
        } else {
            int base = (o - NB_PREP) * 1024 + threadIdx.x;
#pragma unroll
            for (int k = 0; k < 4; ++k) {
                int i = base + k * 256;                // float4 index
                float4 v = ((const float4*)x)[i];
                uint2 ov;
                ov.x = pack2bf(v.x, v.y);
                ov.y = pack2bf(v.z, v.w);
                ((uint2*)xb4)[i] = ov;
            }
        }
    }
}

// ---------------------------------------------------------------------------
// Fused gather + MFMA GEMM — reverted verbatim to the R0 structure (56us,
// counter-proven). R2's x-from-global phase B regressed to 67us: each of the
// 4 waves re-read the whole 16KB A-tile through L1/L2 (4x redundant) and put
// ~200cy global-load latency + vmcnt waits inside the MFMA loop. Occupancy
// never rose (LDS was not the cap), so the LDS saving bought nothing.
// Block owns 64 nodes.
// Phase A: wave w gathers nodes [w*16, w*16+16) into LDS (x rows + normalized
//   agg rows, MFMA-A chunk layout, node dim padded to 65 -> free 2-way).
// Phase B: wave w computes n-tiles {2w,2w+1} for all 64 rows; A from LDS,
//   B from Bperm (L2-hot), bias+ReLU epilogue.
// ---------------------------------------------------------------------------
__global__ __launch_bounds__(256) void gather_gemm_kernel(
    const unsigned short* __restrict__ xb,
    const int* __restrict__ cnt,
    const int* __restrict__ slots,
    const unsigned short* __restrict__ Bperm,
    const float* __restrict__ bias,
    float* __restrict__ out)
{
    __shared__ unsigned short tile[2][16][65][8];   // ~32.5 KB, buf0=x buf1=agg

    const int t = threadIdx.x;
    const int w = t >> 6;
    const int lane = t & 63;
    const int node_base = blockIdx.x * BLK_NODES;
    const int sub = (lane >> 4) & 3;   // node within group of 4
    const int li  = lane & 15;         // column chunk (8 bf16 = 16 B)

    // ---- Phase A: gather + stage ----
    for (int g = 0; g < 4; ++g) {
        int nl = w * 16 + g * 4 + sub;             // node_local 0..63
        int node = node_base + nl;
        float a[8];
#pragma unroll
        for (int i = 0; i < 8; ++i) a[i] = 0.f;
        int d_true = 0;
        uint4 xcopy = make_uint4(0, 0, 0, 0);
        if (node < N_NODES) {
            xcopy = *(const uint4*)(xb + (size_t)node * H + li * 8);
            d_true = cnt[node];
            int d = d_true < CAP ? d_true : CAP;
            const int* sl = slots + node * CAP;
            int e = 0;
            for (; e + 3 < d; e += 4) {
                int i0 = sl[e];
                int i1 = sl[e + 1];
                int i2 = sl[e + 2];
                int i3 = sl[e + 3];
                uint4 u0 = *(const uint4*)(xb + (size_t)i0 * H + li * 8);
                uint4 u1 = *(const uint4*)(xb + (size_t)i1 * H + li * 8);
                uint4 u2 = *(const uint4*)(xb + (size_t)i2 * H + li * 8);
                uint4 u3 = *(const uint4*)(xb + (size_t)i3 * H + li * 8);
                accum8(a, u0);
                accum8(a, u1);
                accum8(a, u2);
                accum8(a, u3);
            }
            for (; e < d; ++e) {
                uint4 u0 = *(const uint4*)(xb + (size_t)sl[e] * H + li * 8);
                accum8(a, u0);
            }
        }
        float inv = 1.0f / fmaxf((float)d_true, 1.0f);
        uint4 o;
        o.x = pack2bf(a[0] * inv, a[1] * inv);
        o.y = pack2bf(a[2] * inv, a[3] * inv);
        o.z = pack2bf(a[4] * inv, a[5] * inv);
        o.w = pack2bf(a[6] * inv, a[7] * inv);
        *(uint4*)&tile[0][li][nl][0] = xcopy;
        *(uint4*)&tile[1][li][nl][0] = o;
    }
    __syncthreads();

    // ---- Phase B: GEMM, wave w owns n-tiles 2w and 2w+1 ----
    const int q  = lane >> 4;
    const int mr = lane & 15;

    v4f acc[4][2];
#pragma unroll
    for (int j = 0; j < 2; ++j) {
        float bv = bias[(2 * w + j) * 16 + mr];
#pragma unroll
        for (int s = 0; s < 4; ++s) acc[s][j] = (v4f){bv, bv, bv, bv};
    }

    const v8s* bp = (const v8s*)Bperm;
#pragma unroll
    for (int ks = 0; ks < 8; ++ks) {
        int buf = ks >> 2;                 // 0: x-part (K 0..127), 1: agg-part
        int lic = (ks & 3) * 4 + q;        // chunk holding cols [ks*32+q*8, +8)
        v8s a[4];
#pragma unroll
        for (int s = 0; s < 4; ++s)
            a[s] = *(const v8s*)&tile[buf][lic][s * 16 + mr][0];
#pragma unroll
        for (int j = 0; j < 2; ++j) {
            v8s bfrag = bp[(ks * 8 + 2 * w + j) * 64 + lane];
#pragma unroll
            for (int s = 0; s < 4; ++s)
                acc[s][j] = __builtin_amdgcn_mfma_f32_16x16x32_bf16(a[s], bfrag, acc[s][j], 0, 0, 0);
        }
    }

    // ---- epilogue: bias already in acc; ReLU + store ----
#pragma unroll
    for (int s = 0; s < 4; ++s) {
#pragma unroll
        for (int r = 0; r < 4; ++r) {
            int row = node_base + s * 16 + q * 4 + r;
            if (row < N_NODES) {
#pragma unroll
                for (int j = 0; j < 2; ++j)
                    out[(size_t)row * H + (2 * w + j) * 16 + mr] = fmaxf(acc[s][j][r], 0.f);
            }
        }
    }
}

extern "C" void kernel_launch(void* const* d_in, const int* in_sizes, int n_in,
                              void* d_out, int out_size, void* d_ws, size_t ws_size,
                              hipStream_t stream) {
    const float* x        = (const float*)d_in[0];
    const int*   senders  = (const int*)d_in[1];
    const int*   receivers= (const int*)d_in[2];
    const float* Ws       = (const float*)d_in[3];
    const float* Wm       = (const float*)d_in[4];
    const float* bias     = (const float*)d_in[5];
    float*       out      = (float*)d_out;

    // workspace layout (~38.9 MB)
    char* p = (char*)d_ws;
    unsigned short* xb    = (unsigned short*)p; p += (size_t)N_NODES * H * sizeof(unsigned short); // 25.6 MB
    unsigned short* Bperm = (unsigned short*)p; p += (size_t)256 * H * sizeof(unsigned short);     // 64 KB
    int* cnt   = (int*)p; p += (size_t)N_NODES * sizeof(int);                                      // 0.4 MB
    int* slots = (int*)p; p += (size_t)N_NODES * CAP * sizeof(int);                                // 12.8 MB

    hipMemsetAsync(cnt, 0, (size_t)N_NODES * sizeof(int), stream);

    prep_fused_kernel<<<NB_TOTAL, 256, 0, stream>>>(
        x, (unsigned int*)xb, Ws, Wm, Bperm, senders, receivers, cnt, slots);
    gather_gemm_kernel<<<N_BLKS, 256, 0, stream>>>(xb, cnt, slots, Bperm, bias, out);
}

// Round 4
// 178.330 us; speedup vs baseline: 1.1560x; 1.0443x over previous
//
#include <hip/hip_runtime.h>

#define N_NODES 100000
#define N_EDGES 600000
#define H 128
#define CAP 32                                           // bucket capacity (Poisson(6), P(>32)~1e-9)

#define NB_FILL 586                                      // 1024 edges/block, 4 consecutive per thread
#define NB_PREP 16
#define NB_CONV4 3125                                    // convert blocks: 1024 float4 each (exact)
#define NB_TOTAL (NB_FILL * 6 + (NB_PREP + NB_CONV4 - NB_FILL * 5))  // 3727

#define BLK_NODES 64
#define N_BLKS ((N_NODES + BLK_NODES - 1) / BLK_NODES)   // 1563

typedef short v8s __attribute__((ext_vector_type(8)));   // 8 bf16 (4 VGPRs)
typedef float v4f __attribute__((ext_vector_type(4)));   // 4 fp32 acc

__device__ __forceinline__ unsigned short f2bf(float f) {
    unsigned int u = __float_as_uint(f);
    u = (u + 0x7fffu + ((u >> 16) & 1u)) >> 16;   // round-nearest-even
    return (unsigned short)u;
}
__device__ __forceinline__ unsigned int pack2bf(float a, float b) {
    return (unsigned int)f2bf(a) | ((unsigned int)f2bf(b) << 16);
}
__device__ __forceinline__ void accum8(float* a, uint4 u) {
    a[0] += __uint_as_float(u.x << 16);
    a[1] += __uint_as_float(u.x & 0xffff0000u);
    a[2] += __uint_as_float(u.y << 16);
    a[3] += __uint_as_float(u.y & 0xffff0000u);
    a[4] += __uint_as_float(u.z << 16);
    a[5] += __uint_as_float(u.z & 0xffff0000u);
    a[6] += __uint_as_float(u.w << 16);
    a[7] += __uint_as_float(u.w & 0xffff0000u);
}

// ---------------------------------------------------------------------------
// Prep (one dispatch, role by blockIdx), FILL interleaved every 6th block so
// CONV's streaming BW hides FILL's atomic latency (R3: +8us, kept).
// R4 micro: each FILL thread takes 4 CONSECUTIVE edges via one int4 load per
// array (perfect coalescing, 1 instr vs 4), issues all 4 independent
// atomicAdds before the dependent slot stores (deeper atomic pipeline).
// FILL itself is pinned at ~50us by device-atomic RMW throughput (~12 G/s):
// R2 (per-receiver private lines) and R3 (overlap) both failed to move it.
// ---------------------------------------------------------------------------
__global__ __launch_bounds__(256) void prep_fused_kernel(
    const float* __restrict__ x, unsigned int* __restrict__ xb4,
    const float* __restrict__ Ws, const float* __restrict__ Wm,
    unsigned short* __restrict__ Bperm,
    const int* __restrict__ senders, const int* __restrict__ receivers,
    int* __restrict__ cnt, int* __restrict__ slots)
{
    int b = blockIdx.x;
    bool isfill = (b % 6 == 0) && (b / 6 < NB_FILL);
    if (isfill) {
        int tid = (b / 6) * 256 + threadIdx.x;           // edge quad index
        if (tid < N_EDGES / 4) {                         // 600000/4 = 150000, exact
            int4 r4 = ((const int4*)receivers)[tid];
            int4 s4 = ((const int4*)senders)[tid];
            int p0 = atomicAdd(&cnt[r4.x], 1);
            int p1 = atomicAdd(&cnt[r4.y], 1);
            int p2 = atomicAdd(&cnt[r4.z], 1);
            int p3 = atomicAdd(&cnt[r4.w], 1);
            if (p0 < CAP) __builtin_nontemporal_store(s4.x, &slots[r4.x * CAP + p0]);
            if (p1 < CAP) __builtin_nontemporal_store(s4.y, &slots[r4.y * CAP + p1]);
            if (p2 < CAP) __builtin_nontemporal_store(s4.z, &slots[r4.z * CAP + p2]);
            if (p3 < CAP) __builtin_nontemporal_store(s4.w, &slots[r4.w * CAP + p3]);
        }
    } else {
        int o = (b < NB_FILL * 6) ? (b - b / 6 - 1) : (b - NB_FILL);
        if (o < NB_PREP) {
            // B-fragment permute: frag f=(kstep*8+ntile)*64+lane holds
            // B[k=kstep*32+q*8+j][n=ntile*16+(lane&15)], B=[Ws;Wm] (K=256,N=128)
            int t = o * 256 + threadIdx.x; // 0..4095
            int kstep = t >> 9;
            int ntile = (t >> 6) & 7;
            int lane  = t & 63;
            int q = lane >> 4;
            int n = ntile * 16 + (lane & 15);
#pragma unroll
            for (int j = 0; j < 8; ++j) {
                int k = kstep * 32 + q * 8 + j;
                float v = (k < H) ? Ws[k * H + n] : Wm[(k - H) * H + n];
                Bperm[(size_t)t * 8 + j] = f2bf(v);
            }
        } else {
            int base = (o - NB_PREP) * 1024 + threadIdx.x;
#pragma unroll
            for (int k = 0; k < 4; ++k) {
                int i = base + k * 256;                // float4 index
                float4 v = ((const float4*)x)[i];
                uint2 ov;
                ov.x = pack2bf(v.x, v.y);
                ov.y = pack2bf(v.z, v.w);
                ((uint2*)xb4)[i] = ov;
            }
        }
    }
}

// ---------------------------------------------------------------------------
// Fused gather + MFMA GEMM. R4 change: 512 threads (8 waves), SAME 64-node
// tile and SAME 33.3KB LDS. Occupancy: LDS caps 4 blocks/CU; at 256thr that
// was 16 waves/CU (50% of slots, measured 30%); at 512thr it is 32 waves/CU
// (100%) -> double the resident phase-A gather chains, which is the
// latency-bound part (MfmaUtil 4%, VALUBusy 23%, HBM 31%: nothing saturated).
// Phase A: wave w gathers nodes [w*8, w*8+8) (2 g-iters); slot indices read
//   as int4 (1 load per 4-batch). Phase B: wave w owns n-tile w only
//   (32 MFMAs, no j loop). Work per block unchanged, block latency ~halved.
// ---------------------------------------------------------------------------
__global__ __launch_bounds__(512) void gather_gemm_kernel(
    const unsigned short* __restrict__ xb,
    const int* __restrict__ cnt,
    const int* __restrict__ slots,
    const unsigned short* __restrict__ Bperm,
    const float* __restrict__ bias,
    float* __restrict__ out)
{
    __shared__ unsigned short tile[2][16][65][8];   // ~32.5 KB, buf0=x buf1=agg

    const int t = threadIdx.x;
    const int w = t >> 6;              // 0..7
    const int lane = t & 63;
    const int node_base = blockIdx.x * BLK_NODES;
    const int sub = (lane >> 4) & 3;   // node within group of 4
    const int li  = lane & 15;         // column chunk (8 bf16 = 16 B)

    // ---- Phase A: gather + stage ----
    for (int g = 0; g < 2; ++g) {
        int nl = w * 8 + g * 4 + sub;              // node_local 0..63
        int node = node_base + nl;
        float a[8];
#pragma unroll
        for (int i = 0; i < 8; ++i) a[i] = 0.f;
        int d_true = 0;
        uint4 xcopy = make_uint4(0, 0, 0, 0);
        if (node < N_NODES) {
            xcopy = *(const uint4*)(xb + (size_t)node * H + li * 8);
            d_true = cnt[node];
            int d = d_true < CAP ? d_true : CAP;
            const int* sl = slots + node * CAP;    // 128B-aligned
            int e = 0;
            for (; e + 3 < d; e += 4) {
                int4 i4 = *(const int4*)&sl[e];    // e%4==0 -> 16B aligned
                uint4 u0 = *(const uint4*)(xb + (size_t)i4.x * H + li * 8);
                uint4 u1 = *(const uint4*)(xb + (size_t)i4.y * H + li * 8);
                uint4 u2 = *(const uint4*)(xb + (size_t)i4.z * H + li * 8);
                uint4 u3 = *(const uint4*)(xb + (size_t)i4.w * H + li * 8);
                accum8(a, u0);
                accum8(a, u1);
                accum8(a, u2);
                accum8(a, u3);
            }
            for (; e < d; ++e) {
                uint4 u0 = *(const uint4*)(xb + (size_t)sl[e] * H + li * 8);
                accum8(a, u0);
            }
        }
        float inv = 1.0f / fmaxf((float)d_true, 1.0f);
        uint4 o;
        o.x = pack2bf(a[0] * inv, a[1] * inv);
        o.y = pack2bf(a[2] * inv, a[3] * inv);
        o.z = pack2bf(a[4] * inv, a[5] * inv);
        o.w = pack2bf(a[6] * inv, a[7] * inv);
        *(uint4*)&tile[0][li][nl][0] = xcopy;
        *(uint4*)&tile[1][li][nl][0] = o;
    }
    __syncthreads();

    // ---- Phase B: GEMM, wave w owns n-tile w ----
    const int q  = lane >> 4;
    const int mr = lane & 15;

    v4f acc[4];
    {
        float bv = bias[w * 16 + mr];
#pragma unroll
        for (int s = 0; s < 4; ++s) acc[s] = (v4f){bv, bv, bv, bv};
    }

    const v8s* bp = (const v8s*)Bperm;
#pragma unroll
    for (int ks = 0; ks < 8; ++ks) {
        int buf = ks >> 2;                 // 0: x-part (K 0..127), 1: agg-part
        int lic = (ks & 3) * 4 + q;        // chunk holding cols [ks*32+q*8, +8)
        v8s a[4];
#pragma unroll
        for (int s = 0; s < 4; ++s)
            a[s] = *(const v8s*)&tile[buf][lic][s * 16 + mr][0];
        v8s bfrag = bp[(ks * 8 + w) * 64 + lane];
#pragma unroll
        for (int s = 0; s < 4; ++s)
            acc[s] = __builtin_amdgcn_mfma_f32_16x16x32_bf16(a[s], bfrag, acc[s], 0, 0, 0);
    }

    // ---- epilogue: bias already in acc; ReLU + store ----
#pragma unroll
    for (int s = 0; s < 4; ++s) {
#pragma unroll
        for (int r = 0; r < 4; ++r) {
            int row = node_base + s * 16 + q * 4 + r;
            if (row < N_NODES)
                out[(size_t)row * H + w * 16 + mr] = fmaxf(acc[s][r], 0.f);
        }
    }
}

extern "C" void kernel_launch(void* const* d_in, const int* in_sizes, int n_in,
                              void* d_out, int out_size, void* d_ws, size_t ws_size,
                              hipStream_t stream) {
    const float* x        = (const float*)d_in[0];
    const int*   senders  = (const int*)d_in[1];
    const int*   receivers= (const int*)d_in[2];
    const float* Ws       = (const float*)d_in[3];
    const float* Wm       = (const float*)d_in[4];
    const float* bias     = (const float*)d_in[5];
    float*       out      = (float*)d_out;

    // workspace layout (~38.9 MB)
    char* p = (char*)d_ws;
    unsigned short* xb    = (unsigned short*)p; p += (size_t)N_NODES * H * sizeof(unsigned short); // 25.6 MB
    unsigned short* Bperm = (unsigned short*)p; p += (size_t)256 * H * sizeof(unsigned short);     // 64 KB
    int* cnt   = (int*)p; p += (size_t)N_NODES * sizeof(int);                                      // 0.4 MB
    int* slots = (int*)p; p += (size_t)N_NODES * CAP * sizeof(int);                                // 12.8 MB

    hipMemsetAsync(cnt, 0, (size_t)N_NODES * sizeof(int), stream);

    prep_fused_kernel<<<NB_TOTAL, 256, 0, stream>>>(
        x, (unsigned int*)xb, Ws, Wm, Bperm, senders, receivers, cnt, slots);
    gather_gemm_kernel<<<N_BLKS, 512, 0, stream>>>(xb, cnt, slots, Bperm, bias, out);
}